// Round 9
// baseline (210.814 us; speedup 1.0000x reference)
//
#include <hip/hip_runtime.h>
#include <hip/hip_bf16.h>

#define NB 16
#define NC 256
#define NPIX 4096

typedef __attribute__((ext_vector_type(8))) short short8;
typedef __attribute__((ext_vector_type(4))) short short4v;
typedef __attribute__((ext_vector_type(4))) float f32x4;

static __device__ __forceinline__ ushort f2bf(float f) {
    __hip_bfloat16 h = __float2bfloat16(f);
    return *(ushort*)&h;
}

static __device__ __forceinline__ void gload_lds16(const ushort* g, ushort* l) {
    __builtin_amdgcn_global_load_lds(
        (const __attribute__((address_space(1))) unsigned int*)g,
        (__attribute__((address_space(3))) unsigned int*)l, 16, 0, 0);
}

// ================= prep: input-only transforms + norm zeroing =================
__global__ void __launch_bounds__(256) prep_k(
    const float* __restrict__ e, const float* __restrict__ pam,
    const float* __restrict__ qw, const float* __restrict__ kw,
    const float* __restrict__ vw, const float* __restrict__ pw,
    ushort* __restrict__ maxeT, ushort* __restrict__ pamT,
    ushort* __restrict__ wqT, ushort* __restrict__ wkT,
    ushort* __restrict__ pbf, ushort* __restrict__ vwT,
    float* __restrict__ qnorm, float* __restrict__ knorm) {
    __shared__ float smem[9216];
    int blk = blockIdx.x, t = threadIdx.x;
    if (blk < 1024) {
        int b = blk >> 6, c0 = (blk & 63) * 4;
        int py = t >> 4, px4 = (t & 15) * 4;
        float s[4];
#pragma unroll
        for (int cc = 0; cc < 4; ++cc) {
            const float* p = e + (size_t)(b * 256 + c0 + cc) * NPIX;
            float a = 0.f;
#pragma unroll
            for (int r = 0; r < 4; ++r) {
                float4 v = *(const float4*)(p + (py * 4 + r) * 64 + px4);
                a += v.x + v.y + v.z + v.w;
            }
            s[cc] = a * 0.0625f;
        }
        short4v v;
#pragma unroll
        for (int cc = 0; cc < 4; ++cc) v[cc] = (short)f2bf(s[cc]);
        *(short4v*)(maxeT + (size_t)b * 65536 + (size_t)t * 256 + c0) = v;
    } else if (blk < 1280) {
        int bb = blk - 1024;
        int b = bb >> 4, cg = bb & 15;
        float (*lt)[256] = (float(*)[256])smem;
#pragma unroll
        for (int cc = 0; cc < 16; ++cc)
            lt[cc][t] = pam[(size_t)(b * 256 + cg * 16 + cc) * 256 + t];
        __syncthreads();
        ushort* dstb = pamT + (size_t)b * 65536 + (size_t)t * 256 + cg * 16;
#pragma unroll
        for (int g = 0; g < 2; ++g) {
            short8 v;
#pragma unroll
            for (int k = 0; k < 8; ++k) v[k] = (short)f2bf(lt[g * 8 + k][t]);
            *(short8*)(dstb + g * 8) = v;
        }
    } else if (blk < 1792) {
        int idx = blk - 1280;
        const float* src = (idx < 256) ? qw : kw;
        ushort* dst = (idx < 256) ? wqT : wkT;
        int o = idx & 255;
        float wv[9];
#pragma unroll
        for (int j = 0; j < 9; ++j) wv[j] = src[(size_t)o * 2304 + t * 9 + j];
#pragma unroll
        for (int j = 0; j < 9; ++j) dst[(size_t)j * 65536 + (size_t)o * 256 + t] = f2bf(wv[j]);
    } else if (blk < 1808) {
        int base = (blk - 1792) * 4096;
        for (int g = 0; g < 16; ++g) {
            int idx = base + g * 256 + t;
            pbf[idx] = f2bf(pw[idx]);
        }
    } else if (blk < 1872) {
        int d0 = (blk - 1808) * 4;
        float* lt = smem;   // flat [4][2304]
        for (int u = 0; u < 36; ++u) lt[u * 256 + t] = vw[(size_t)d0 * 2304 + u * 256 + t];
        __syncthreads();
#pragma unroll
        for (int r = 0; r < 9; ++r) {
            int idx = r * 256 + t;
            int i = idx / 9, j = idx % 9;
            short4v v;
#pragma unroll
            for (int dd = 0; dd < 4; ++dd) v[dd] = (short)f2bf(lt[dd * 2304 + idx]);
            *(short4v*)(vwT + ((size_t)(j * 256 + i)) * 256 + d0) = v;
        }
    } else {
        for (int g = 0; g < 16; ++g) {
            qnorm[g * 256 + t] = 0.f;
            knorm[g * 256 + t] = 0.f;
        }
    }
}

// ---- conv16 v2: LDS-staged B (once) + pipelined A chunks; unnormalized out ---
__global__ void __launch_bounds__(256, 2) conv16_mfma(const ushort* __restrict__ maxeT,
                                                      const ushort* __restrict__ pamT,
                                                      const ushort* __restrict__ wqT,
                                                      const ushort* __restrict__ wkT,
                                                      ushort* __restrict__ qb,
                                                      ushort* __restrict__ kTb,
                                                      float* __restrict__ qnorm,
                                                      float* __restrict__ knorm) {
    int blk = blockIdx.x;
    int qk = blk >> 8;
    int b  = (blk >> 4) & 15;
    int og = (blk >> 2) & 3;
    int tg = blk & 3;
    const ushort* inT = qk ? pamT : maxeT;
    const ushort* wt  = qk ? wkT : wqT;
    ushort* outp      = qk ? kTb : qb;
    float* nrm        = qk ? knorm : qnorm;
    int tid = threadIdx.x, wid = tid >> 6, lane = tid & 63;
    int wm = wid >> 1, wn = wid & 1;
    int kq = lane >> 4, l16 = lane & 15;
    int ty0 = tg * 4;
    __shared__ ushort Bs[96][256];
    __shared__ ushort As[2][64][64];
    const ushort* itb = inT + (size_t)b * 65536;
    {
#pragma unroll
        for (int j = 0; j < 12; ++j) {
            int d = (j * 4 + wid) * 64 + lane;
            int tok = d >> 5, u = d & 31;
            int lr = tok >> 4, tx = tok & 15;
            int gy = min(max(ty0 - 1 + lr, 0), 15);
            gload_lds16(itb + (gy * 16 + tx) * 256 + ((u ^ (tok & 7)) * 8),
                        &Bs[0][0] + (size_t)(j * 4 + wid) * 512);
        }
    }
    int aoff[2];
#pragma unroll
    for (int j = 0; j < 2; ++j) {
        int d = (j * 4 + wid) * 64 + lane;
        int o = d >> 3, u = d & 7;
        aoff[j] = (og * 64 + o) * 256 + ((u ^ (o & 7)) * 8);
    }
    auto stageA = [&](int s, int buf) {
        const ushort* base = wt + (size_t)(s >> 2) * 65536 + (s & 3) * 64;
#pragma unroll
        for (int j = 0; j < 2; ++j)
            gload_lds16(base + aoff[j], &As[buf][0][0] + (size_t)(j * 4 + wid) * 512);
    };
    stageA(0, 0);
    stageA(1, 1);
    __syncthreads();
    f32x4 acc[2][2];
#pragma unroll
    for (int mf = 0; mf < 2; ++mf)
#pragma unroll
        for (int nf = 0; nf < 2; ++nf) acc[mf][nf] = (f32x4){0.f, 0.f, 0.f, 0.f};
    const short8 zf = {};
    for (int s = 0; s < 36; ++s) {
        int tap = s >> 2, kh = s & 3;
        int dy = tap / 3 - 1, dx = tap % 3 - 1;
        const ushort* bp[2]; bool ok[2]; int lt7[2];
#pragma unroll
        for (int nf = 0; nf < 2; ++nf) {
            int n = tg * 64 + wn * 32 + nf * 16 + l16;
            int ny = (n >> 4) + dy, nx = (n & 15) + dx;
            ok[nf] = ((unsigned)ny < 16u) && ((unsigned)nx < 16u);
            int lrc = min(max(ny - ty0 + 1, 0), 5);
            int nxc = min(max(nx, 0), 15);
            int ltok = lrc * 16 + nxc;
            bp[nf] = &Bs[ltok][0];
            lt7[nf] = ltok & 7;
        }
#pragma unroll
        for (int kc = 0; kc < 2; ++kc) {
            int ua = kc * 4 + kq;
            int ub = kh * 8 + kc * 4 + kq;
            short8 af[2], bfr[2];
#pragma unroll
            for (int mf = 0; mf < 2; ++mf) {
                int o = wm * 32 + mf * 16 + l16;
                af[mf] = *(const short8*)(&As[s & 1][o][(ua ^ (o & 7)) * 8]);
            }
#pragma unroll
            for (int nf = 0; nf < 2; ++nf) {
                short8 v = *(const short8*)(bp[nf] + ((ub ^ lt7[nf]) * 8));
                bfr[nf] = ok[nf] ? v : zf;
            }
#pragma unroll
            for (int mf = 0; mf < 2; ++mf)
#pragma unroll
                for (int nf = 0; nf < 2; ++nf)
                    acc[mf][nf] = __builtin_amdgcn_mfma_f32_16x16x32_bf16(af[mf], bfr[nf], acc[mf][nf], 0, 0, 0);
        }
        __syncthreads();
        if (s + 2 < 36) stageA(s + 2, s & 1);
    }
    float ss[2][4];
#pragma unroll
    for (int mf = 0; mf < 2; ++mf)
#pragma unroll
        for (int r = 0; r < 4; ++r) ss[mf][r] = 0.f;
#pragma unroll
    for (int mf = 0; mf < 2; ++mf)
#pragma unroll
        for (int nf = 0; nf < 2; ++nf)
#pragma unroll
            for (int r = 0; r < 4; ++r) ss[mf][r] += acc[mf][nf][r] * acc[mf][nf][r];
#pragma unroll
    for (int mf = 0; mf < 2; ++mf)
#pragma unroll
        for (int r = 0; r < 4; ++r) {
#pragma unroll
            for (int off = 1; off < 16; off <<= 1) ss[mf][r] += __shfl_xor(ss[mf][r], off, 64);
        }
    if (l16 == 0) {
#pragma unroll
        for (int mf = 0; mf < 2; ++mf)
#pragma unroll
            for (int r = 0; r < 4; ++r)
                atomicAdd(&nrm[b * 256 + og * 64 + wm * 32 + mf * 16 + kq * 4 + r], ss[mf][r]);
    }
    ushort* ob = outp + (size_t)b * 65536;
#pragma unroll
    for (int mf = 0; mf < 2; ++mf)
#pragma unroll
        for (int nf = 0; nf < 2; ++nf) {
            int col = tg * 64 + wn * 32 + nf * 16 + l16;
#pragma unroll
            for (int r = 0; r < 4; ++r) {
                int row = og * 64 + wm * 32 + mf * 16 + kq * 4 + r;
                ob[(size_t)row * 256 + col] = f2bf(acc[mf][nf][r]);
            }
        }
}

// ---- attn via MFMA + norms + softmax; 64 blocks; attnT[d][c] bf16 ------------
__global__ void __launch_bounds__(512) attn_mfma(const ushort* __restrict__ qb,
                                                 const ushort* __restrict__ kTb,
                                                 const float* __restrict__ qnorm,
                                                 const float* __restrict__ knorm,
                                                 ushort* __restrict__ attnT) {
    int blk = blockIdx.x;
    int b = (blk & 7) + 8 * ((blk >> 3) & 1);
    int cg = blk >> 4;
    int tid = threadIdx.x, wid = tid >> 6, lane = tid & 63;
    int rw = wid & 3, chf = wid >> 2;
    int kq = lane >> 4, l16 = lane & 15;
    int c0w = cg * 64 + rw * 16;
    int lrow = rw * 16 + kq * 4;
    f32x4 acc[8];
#pragma unroll
    for (int nf = 0; nf < 8; ++nf) acc[nf] = (f32x4){0.f, 0.f, 0.f, 0.f};
    const ushort* qp = qb + (size_t)b * 65536;
    const ushort* kp = kTb + (size_t)b * 65536 + (size_t)(chf * 128) * 256;
    for (int kc = 0; kc < 8; ++kc) {
        short8 af = *(const short8*)(qp + (size_t)(c0w + l16) * 256 + kc * 32 + kq * 8);
#pragma unroll
        for (int nf = 0; nf < 8; ++nf) {
            short8 bf = *(const short8*)(kp + (size_t)(nf * 16 + l16) * 256 + kc * 32 + kq * 8);
            acc[nf] = __builtin_amdgcn_mfma_f32_16x16x32_bf16(af, bf, acc[nf], 0, 0, 0);
        }
    }
    float rq[4], rk[8];
#pragma unroll
    for (int r = 0; r < 4; ++r)
        rq[r] = rsqrtf(fmaxf(qnorm[b * 256 + c0w + kq * 4 + r], 1e-24f)) * 0.0625f;
#pragma unroll
    for (int nf = 0; nf < 8; ++nf)
        rk[nf] = rsqrtf(fmaxf(knorm[b * 256 + chf * 128 + nf * 16 + l16], 1e-24f));
#pragma unroll
    for (int nf = 0; nf < 8; ++nf)
#pragma unroll
        for (int r = 0; r < 4; ++r) acc[nf][r] *= rq[r] * rk[nf];
    __shared__ float red[64][2];
    float m4[4], s4[4];
#pragma unroll
    for (int r = 0; r < 4; ++r) {
        float m = -1e30f;
#pragma unroll
        for (int nf = 0; nf < 8; ++nf) m = fmaxf(m, acc[nf][r]);
#pragma unroll
        for (int off = 1; off < 16; off <<= 1) m = fmaxf(m, __shfl_xor(m, off, 64));
        m4[r] = m;
    }
    if (l16 == 0) {
#pragma unroll
        for (int r = 0; r < 4; ++r) red[lrow + r][chf] = m4[r];
    }
    __syncthreads();
#pragma unroll
    for (int r = 0; r < 4; ++r) m4[r] = fmaxf(red[lrow + r][0], red[lrow + r][1]);
    __syncthreads();
#pragma unroll
    for (int r = 0; r < 4; ++r) {
        float s = 0.f;
#pragma unroll
        for (int nf = 0; nf < 8; ++nf) {
            float ex = __expf(acc[nf][r] - m4[r]);
            acc[nf][r] = ex;
            s += ex;
        }
#pragma unroll
        for (int off = 1; off < 16; off <<= 1) s += __shfl_xor(s, off, 64);
        s4[r] = s;
    }
    if (l16 == 0) {
#pragma unroll
        for (int r = 0; r < 4; ++r) red[lrow + r][chf] = s4[r];
    }
    __syncthreads();
#pragma unroll
    for (int r = 0; r < 4; ++r) {
        float inv = 1.0f / (red[lrow + r][0] + red[lrow + r][1]);
#pragma unroll
        for (int nf = 0; nf < 8; ++nf) acc[nf][r] *= inv;
    }
    ushort* ap = attnT + (size_t)b * 65536;
#pragma unroll
    for (int nf = 0; nf < 8; ++nf) {
        int d = chf * 128 + nf * 16 + l16;
        short4v v;
#pragma unroll
        for (int r = 0; r < 4; ++r) v[r] = (short)f2bf(acc[nf][r]);
        *(short4v*)(ap + (size_t)d * 256 + c0w + kq * 4) = v;
    }
}

// ---- Mbf[b][o][d] = bf16( sum_c pbf[o,c] * attnT[d,c] ); 64 blocks -----------
__global__ void __launch_bounds__(512) mproj_mfma(const ushort* __restrict__ pbf,
                                                  const ushort* __restrict__ attnT,
                                                  ushort* __restrict__ Mbf) {
    int blk = blockIdx.x;
    int b = (blk & 7) + 8 * ((blk >> 3) & 1);
    int og = blk >> 4;
    int tid = threadIdx.x, wid = tid >> 6, lane = tid & 63;
    int rw = wid & 3, chf = wid >> 2;
    int kq = lane >> 4, l16 = lane & 15;
    int o0w = og * 64 + rw * 16;
    f32x4 acc[8];
#pragma unroll
    for (int nf = 0; nf < 8; ++nf) acc[nf] = (f32x4){0.f, 0.f, 0.f, 0.f};
    const ushort* ap = attnT + (size_t)b * 65536 + (size_t)(chf * 128) * 256;
    for (int kc = 0; kc < 8; ++kc) {
        short8 af = *(const short8*)(pbf + (size_t)(o0w + l16) * 256 + kc * 32 + kq * 8);
#pragma unroll
        for (int nf = 0; nf < 8; ++nf) {
            short8 bf = *(const short8*)(ap + (size_t)(nf * 16 + l16) * 256 + kc * 32 + kq * 8);
            acc[nf] = __builtin_amdgcn_mfma_f32_16x16x32_bf16(af, bf, acc[nf], 0, 0, 0);
        }
    }
    ushort* mb = Mbf + (size_t)b * 65536;
#pragma unroll
    for (int nf = 0; nf < 8; ++nf)
#pragma unroll
        for (int r = 0; r < 4; ++r)
            mb[(size_t)(o0w + kq * 4 + r) * 256 + chf * 128 + nf * 16 + l16] = f2bf(acc[nf][r]);
}

// ---- wbf[b][j][o][i] = bf16( sum_d Mbf[b,o,d] * vwT[j,i,d] ) via MFMA --------
__global__ void __launch_bounds__(512) weff_mfma(const ushort* __restrict__ Mbf,
                                                 const ushort* __restrict__ vwT,
                                                 ushort* __restrict__ wbf) {
    int blk = blockIdx.x;
    int i = blk >> 3;
    int b = (blk & 7) + 8 * (i >> 4);
    int j = i & 15;
    if (j >= 9) return;
    int tid = threadIdx.x;
    int wid = tid >> 6, lane = tid & 63;
    int wm = wid >> 1, wn = wid & 1;
    int kq = lane >> 4, l16 = lane & 15;
    f32x4 acc[4][8];
#pragma unroll
    for (int mf = 0; mf < 4; ++mf)
#pragma unroll
        for (int nf = 0; nf < 8; ++nf) acc[mf][nf] = (f32x4){0.f, 0.f, 0.f, 0.f};
    const ushort* abase = Mbf + (size_t)b * 65536 + (size_t)(wm * 64 + l16) * 256 + kq * 8;
    const ushort* bbase = vwT + (size_t)(j * 256 + wn * 128 + l16) * 256 + kq * 8;
    for (int kc = 0; kc < 8; ++kc) {
        int d0 = kc * 32;
        short8 af[4], bfr[8];
#pragma unroll
        for (int mf = 0; mf < 4; ++mf) af[mf] = *(const short8*)(abase + mf * 16 * 256 + d0);
#pragma unroll
        for (int nf = 0; nf < 8; ++nf) bfr[nf] = *(const short8*)(bbase + nf * 16 * 256 + d0);
#pragma unroll
        for (int mf = 0; mf < 4; ++mf)
#pragma unroll
            for (int nf = 0; nf < 8; ++nf)
                acc[mf][nf] = __builtin_amdgcn_mfma_f32_16x16x32_bf16(af[mf], bfr[nf], acc[mf][nf], 0, 0, 0);
    }
    ushort* wout = wbf + ((size_t)(b * 9 + j)) * 65536;
#pragma unroll
    for (int mf = 0; mf < 4; ++mf) {
        int o = wm * 64 + mf * 16 + kq * 4;
#pragma unroll
        for (int nf = 0; nf < 8; ++nf) {
            int ic = wn * 128 + nf * 16 + l16;
#pragma unroll
            for (int r = 0; r < 4; ++r)
                wout[(size_t)(o + r) * 256 + ic] = f2bf(acc[mf][nf][r]);
        }
    }
}

// ---- big conv v6: full-o block (256 o), 4-row tile, wave 64o x 2row x 64px ---
// grid 256 = [b_hi][pt 16][b_lo 3]; 8 waves: wy(2 row-pairs) x wo(4 o-chunks)
// pipeline: compute(t); barrier; issue A(t+2)  -> loads land during next tap
__global__ void __launch_bounds__(512, 2) bigconv_mfma(const float* __restrict__ e,
                                                       const ushort* __restrict__ wbf,
                                                       float* __restrict__ out) {
    int blk = blockIdx.x;
    int b = (blk & 7) + 8 * (blk >> 7);
    int pt = (blk >> 3) & 15;
    int y0 = pt * 4;
    int tid = threadIdx.x, wid = tid >> 6, lane = tid & 63;
    int wy = wid >> 2, wo = wid & 3;     // wy: rows {2wy,2wy+1}; wo: 64-o chunk
    int kq = lane >> 4, l16 = lane & 15;
    __shared__ ushort Bs[6][64][64];     // 48 KB: rows y0-1..y0+4
    __shared__ ushort As[2][256][64];    // 64 KB dbuf (all 256 o)
    f32x4 acc[4][8];
#pragma unroll
    for (int mf = 0; mf < 4; ++mf)
#pragma unroll
        for (int nf = 0; nf < 8; ++nf) acc[mf][nf] = (f32x4){0.f, 0.f, 0.f, 0.f};
    const float* eb = e + (size_t)b * NC * NPIX;
    const ushort* wb = wbf + (size_t)b * 589824;
    const short8 zf = {};
    // B-stage roles: 384 active = 32 ch-pairs x 6 rows x 2 px-halves
    int c2 = tid & 31, rr = tid >> 5;
    int sr = rr >> 1, sq = rr & 1;
    bool bstage = (rr < 12);
    int syc = min(max(y0 - 1 + sr, 0), 63);
    // A-stage invariants: 4 gload16/thread per tap = 256 o x 64 i
    int ao[4], asd[4];
#pragma unroll
    for (int j = 0; j < 4; ++j) {
        int du = (j * 8 + wid) * 64 + lane;
        ao[j] = du >> 3;
        asd[j] = (du & 7) ^ (ao[j] & 7);
    }
    auto stageA = [&](int tap, int buf, int ci) {
        const ushort* base = wb + (size_t)tap * 65536 + ci * 64;
#pragma unroll
        for (int j = 0; j < 4; ++j)
            gload_lds16(base + (size_t)ao[j] * 256 + asd[j] * 8,
                        &As[buf][0][0] + (size_t)(j * 8 + wid) * 512);
    };

    for (int ci = 0; ci < 4; ++ci) {
        // ---- stage B: 6 rows x 64 px x 64 ch, fused NHWC + swizzle ----
        if (bstage) {
            const float* s0 = eb + ((size_t)(ci * 64 + 2 * c2) * 64 + syc) * 64 + sq * 32;
            const float* s1 = s0 + NPIX;
            uint* bsrow = (uint*)&Bs[sr][0][0];
#pragma unroll
            for (int h = 0; h < 2; ++h) {
                float4 va[4], vb[4];
#pragma unroll
                for (int q = 0; q < 4; ++q) va[q] = *(const float4*)(s0 + h * 16 + q * 4);
#pragma unroll
                for (int q = 0; q < 4; ++q) vb[q] = *(const float4*)(s1 + h * 16 + q * 4);
#pragma unroll
                for (int q = 0; q < 4; ++q) {
#pragma unroll
                    for (int m2 = 0; m2 < 4; ++m2) {
                        int px = sq * 32 + h * 16 + q * 4 + m2;
                        float f0 = ((const float*)&va[q])[m2];
                        float f1 = ((const float*)&vb[q])[m2];
                        uint pk = (uint)f2bf(f0) | ((uint)f2bf(f1) << 16);
                        int s = (c2 >> 2) ^ (px & 7);
                        bsrow[px * 32 + s * 4 + (c2 & 3)] = pk;
                    }
                }
            }
        }
        // ---- prologue: stage A(0)->buf0, A(1)->buf1 ----
        stageA(0, 0, ci);
        stageA(1, 1, ci);
        __syncthreads();   // drains B writes + A(0)/A(1) loads
        for (int tap = 0; tap < 9; ++tap) {
            int cur = tap & 1;
            // ---- compute tap from As[cur] + Bs ----
            {
                int dy = tap / 3 - 1, dx = tap % 3 - 1;
                const ushort* bp[8]; bool ok[8]; int p7[8];
#pragma unroll
                for (int nf = 0; nf < 8; ++nf) {
                    int h = nf >> 2;
                    int yabs = y0 + wy * 2 + h + dy;
                    int rl = wy * 2 + h + dy + 1;      // 0..5
                    int pxr = (nf & 3) * 16 + l16 + dx;
                    ok[nf] = ((unsigned)yabs < 64u) && ((unsigned)pxr < 64u);
                    int pxc = min(max(pxr, 0), 63);
                    bp[nf] = &Bs[rl][pxc][0];
                    p7[nf] = pxc & 7;
                }
#pragma unroll
                for (int kc = 0; kc < 2; ++kc) {
                    int sd = kc * 4 + kq;
                    short8 af[4];
#pragma unroll
                    for (int mf = 0; mf < 4; ++mf) {
                        int o = wo * 64 + mf * 16 + l16;
                        af[mf] = *(const short8*)(&As[cur][o][(sd ^ (o & 7)) * 8]);
                    }
                    short8 bfr[8];
#pragma unroll
                    for (int nf = 0; nf < 8; ++nf) {
                        short8 v = *(const short8*)(bp[nf] + (sd ^ p7[nf]) * 8);
                        bfr[nf] = ok[nf] ? v : zf;
                    }
#pragma unroll
                    for (int mf = 0; mf < 4; ++mf)
#pragma unroll
                        for (int nf = 0; nf < 8; ++nf)
                            acc[mf][nf] = __builtin_amdgcn_mfma_f32_16x16x32_bf16(af[mf], bfr[nf], acc[mf][nf], 0, 0, 0);
                }
            }
            __syncthreads();   // drains A(tap+1) (issued last tap, fully covered)
            if (tap + 2 < 9) stageA(tap + 2, cur, ci);
        }
        // loop continues: B overwrite is safe (barrier at end of tap 8)
    }
    // ---- epilogue: + residual ----
    float* ob = out + (size_t)b * NC * NPIX;
#pragma unroll
    for (int mf = 0; mf < 4; ++mf) {
        int o = wo * 64 + mf * 16 + kq * 4;
#pragma unroll
        for (int nf = 0; nf < 8; ++nf) {
            int y = y0 + wy * 2 + (nf >> 2);
            int p = y * 64 + (nf & 3) * 16 + l16;
#pragma unroll
            for (int r = 0; r < 4; ++r) {
                size_t idx = (size_t)(o + r) * NPIX + p;
                ob[idx] = acc[mf][nf][r] + eb[idx];
            }
        }
    }
}

extern "C" void kernel_launch(void* const* d_in, const int* in_sizes, int n_in,
                              void* d_out, int out_size, void* d_ws, size_t ws_size,
                              hipStream_t stream) {
    const float* e   = (const float*)d_in[0];
    const float* pam = (const float*)d_in[1];
    const float* qw  = (const float*)d_in[2];
    const float* kw  = (const float*)d_in[3];
    const float* vw  = (const float*)d_in[4];
    const float* pw  = (const float*)d_in[5];
    float* out = (float*)d_out;
    float* ws  = (float*)d_ws;

    ushort* wbf  = (ushort*)ws;                      // 9,437,184 ushorts (18.9MB)
    float*  S    = ws + 4718592;
    ushort* maxeT = (ushort*)S;
    ushort* pamT  = (ushort*)(S + 524288);
    ushort* wqT   = (ushort*)(S + 1048576);
    ushort* wkT   = (ushort*)(S + 1343488);
    ushort* pbf   = (ushort*)(S + 1638400);
    ushort* vwT   = (ushort*)(S + 1671168);
    float*  qnorm = S + 1966080;
    float*  knorm = S + 1970176;
    ushort* qb    = (ushort*)ws;
    ushort* kTb   = (ushort*)(ws + 524288);
    ushort* attnT = maxeT;
    ushort* Mbf   = pamT;

    prep_k<<<1873, 256, 0, stream>>>(e, pam, qw, kw, vw, pw,
                                     maxeT, pamT, wqT, wkT, pbf, vwT, qnorm, knorm);
    conv16_mfma<<<512, 256, 0, stream>>>(maxeT, pamT, wqT, wkT, qb, kTb, qnorm, knorm);
    attn_mfma<<<64, 512, 0, stream>>>(qb, kTb, qnorm, knorm, attnT);
    mproj_mfma<<<64, 512, 0, stream>>>(pbf, attnT, Mbf);
    weff_mfma<<<256, 512, 0, stream>>>(Mbf, vwT, wbf);
    bigconv_mfma<<<256, 512, 0, stream>>>(e, wbf, out);
}

// Round 10
// 180.720 us; speedup vs baseline: 1.1665x; 1.1665x over previous
//
#include <hip/hip_runtime.h>
#include <hip/hip_bf16.h>

#define NB 16
#define NC 256
#define NPIX 4096

typedef __attribute__((ext_vector_type(8))) short short8;
typedef __attribute__((ext_vector_type(4))) short short4v;
typedef __attribute__((ext_vector_type(4))) float f32x4;

static __device__ __forceinline__ ushort f2bf(float f) {
    __hip_bfloat16 h = __float2bfloat16(f);
    return *(ushort*)&h;
}

static __device__ __forceinline__ void gload_lds16(const ushort* g, ushort* l) {
    __builtin_amdgcn_global_load_lds(
        (const __attribute__((address_space(1))) unsigned int*)g,
        (__attribute__((address_space(3))) unsigned int*)l, 16, 0, 0);
}

// ================= prep: fused nhwc+pool, transforms, norm zeroing ============
// blocks: [0,256) nhwc+pool (b x 4-row group) | [256,512) pamtr |
// [512,1024) wtap | [1024,1040) projcast | [1040,1104) vwT | 1104 zero norms
__global__ void __launch_bounds__(256) prep_k(
    const float* __restrict__ e, const float* __restrict__ pam,
    const float* __restrict__ qw, const float* __restrict__ kw,
    const float* __restrict__ vw, const float* __restrict__ pw,
    ushort* __restrict__ et, ushort* __restrict__ maxeT, ushort* __restrict__ pamT,
    ushort* __restrict__ wqT, ushort* __restrict__ wkT,
    ushort* __restrict__ pbf, ushort* __restrict__ vwT,
    float* __restrict__ qnorm, float* __restrict__ knorm) {
    __shared__ float smem[16384];   // 64 KB
    int blk = blockIdx.x, t = threadIdx.x;
    if (blk < 256) {
        // e NCHW f32 -> et[b][y][x][c] bf16 (XOR-swizzle transpose) + 4x4 pool
        int b = blk >> 4, py = blk & 15;
        float (*lt)[64] = (float(*)[64])smem;   // [256][64]
        float pool[16];
#pragma unroll
        for (int rr = 0; rr < 16; ++rr) pool[rr] = 0.f;
        int x4 = (t & 15) * 4;
        int cg = t >> 4;
        for (int r = 0; r < 4; ++r) {
            int y = py * 4 + r;
            if (r) __syncthreads();
            const float* ep = e + (size_t)b * NC * NPIX + y * 64;
#pragma unroll
            for (int rr = 0; rr < 16; ++rr) {
                int c = rr * 16 + cg;
                float4 v = *(const float4*)(ep + (size_t)c * NPIX + x4);
                pool[rr] += v.x + v.y + v.z + v.w;
                int s = (c >> 3) & 31;
                lt[c][(x4 + 0) ^ s] = v.x;
                lt[c][(x4 + 1) ^ s] = v.y;
                lt[c][(x4 + 2) ^ s] = v.z;
                lt[c][(x4 + 3) ^ s] = v.w;
            }
            __syncthreads();
            int l = t & 31, c0 = l * 8;
            ushort* op = et + ((size_t)(b * 64 + y) * 64) * 256;
            for (int rx = 0; rx < 8; ++rx) {
                int x = rx * 8 + (t >> 5);
                short8 v;
#pragma unroll
                for (int k = 0; k < 8; ++k) v[k] = (short)f2bf(lt[c0 + k][x ^ l]);
                *(short8*)(op + (size_t)x * 256 + c0) = v;
            }
        }
        int tok = py * 16 + (t & 15);
        ushort* md = maxeT + (size_t)b * 65536 + (size_t)tok * 256;
#pragma unroll
        for (int rr = 0; rr < 16; ++rr)
            md[rr * 16 + cg] = f2bf(pool[rr] * 0.0625f);
    } else if (blk < 512) {
        int bb = blk - 256;
        int b = bb >> 4, cg = bb & 15;
        float (*lt)[256] = (float(*)[256])smem;
#pragma unroll
        for (int cc = 0; cc < 16; ++cc)
            lt[cc][t] = pam[(size_t)(b * 256 + cg * 16 + cc) * 256 + t];
        __syncthreads();
        ushort* dstb = pamT + (size_t)b * 65536 + (size_t)t * 256 + cg * 16;
#pragma unroll
        for (int g = 0; g < 2; ++g) {
            short8 v;
#pragma unroll
            for (int k = 0; k < 8; ++k) v[k] = (short)f2bf(lt[g * 8 + k][t]);
            *(short8*)(dstb + g * 8) = v;
        }
    } else if (blk < 1024) {
        int idx = blk - 512;
        const float* src = (idx < 256) ? qw : kw;
        ushort* dst = (idx < 256) ? wqT : wkT;
        int o = idx & 255;
        float wv[9];
#pragma unroll
        for (int j = 0; j < 9; ++j) wv[j] = src[(size_t)o * 2304 + t * 9 + j];
#pragma unroll
        for (int j = 0; j < 9; ++j) dst[(size_t)j * 65536 + (size_t)o * 256 + t] = f2bf(wv[j]);
    } else if (blk < 1040) {
        int base = (blk - 1024) * 4096;
        for (int g = 0; g < 16; ++g) {
            int idx = base + g * 256 + t;
            pbf[idx] = f2bf(pw[idx]);
        }
    } else if (blk < 1104) {
        int d0 = (blk - 1040) * 4;
        float* lt = smem;   // flat [4][2304]
        for (int u = 0; u < 36; ++u) lt[u * 256 + t] = vw[(size_t)d0 * 2304 + u * 256 + t];
        __syncthreads();
#pragma unroll
        for (int r = 0; r < 9; ++r) {
            int idx = r * 256 + t;
            int i = idx / 9, j = idx % 9;
            short4v v;
#pragma unroll
            for (int dd = 0; dd < 4; ++dd) v[dd] = (short)f2bf(lt[dd * 2304 + idx]);
            *(short4v*)(vwT + ((size_t)(j * 256 + i)) * 256 + d0) = v;
        }
    } else {
        for (int g = 0; g < 16; ++g) {
            qnorm[g * 256 + t] = 0.f;
            knorm[g * 256 + t] = 0.f;
        }
    }
}

// ---- conv16: LDS-staged B (once) + pipelined A chunks; unnormalized out ------
__global__ void __launch_bounds__(256, 2) conv16_mfma(const ushort* __restrict__ maxeT,
                                                      const ushort* __restrict__ pamT,
                                                      const ushort* __restrict__ wqT,
                                                      const ushort* __restrict__ wkT,
                                                      ushort* __restrict__ qb,
                                                      ushort* __restrict__ kTb,
                                                      float* __restrict__ qnorm,
                                                      float* __restrict__ knorm) {
    int blk = blockIdx.x;
    int qk = blk >> 8;
    int b  = (blk >> 4) & 15;
    int og = (blk >> 2) & 3;
    int tg = blk & 3;
    const ushort* inT = qk ? pamT : maxeT;
    const ushort* wt  = qk ? wkT : wqT;
    ushort* outp      = qk ? kTb : qb;
    float* nrm        = qk ? knorm : qnorm;
    int tid = threadIdx.x, wid = tid >> 6, lane = tid & 63;
    int wm = wid >> 1, wn = wid & 1;
    int kq = lane >> 4, l16 = lane & 15;
    int ty0 = tg * 4;
    __shared__ ushort Bs[96][256];
    __shared__ ushort As[2][64][64];
    const ushort* itb = inT + (size_t)b * 65536;
    {
#pragma unroll
        for (int j = 0; j < 12; ++j) {
            int d = (j * 4 + wid) * 64 + lane;
            int tok = d >> 5, u = d & 31;
            int lr = tok >> 4, tx = tok & 15;
            int gy = min(max(ty0 - 1 + lr, 0), 15);
            gload_lds16(itb + (gy * 16 + tx) * 256 + ((u ^ (tok & 7)) * 8),
                        &Bs[0][0] + (size_t)(j * 4 + wid) * 512);
        }
    }
    int aoff[2];
#pragma unroll
    for (int j = 0; j < 2; ++j) {
        int d = (j * 4 + wid) * 64 + lane;
        int o = d >> 3, u = d & 7;
        aoff[j] = (og * 64 + o) * 256 + ((u ^ (o & 7)) * 8);
    }
    auto stageA = [&](int s, int buf) {
        const ushort* base = wt + (size_t)(s >> 2) * 65536 + (s & 3) * 64;
#pragma unroll
        for (int j = 0; j < 2; ++j)
            gload_lds16(base + aoff[j], &As[buf][0][0] + (size_t)(j * 4 + wid) * 512);
    };
    stageA(0, 0);
    stageA(1, 1);
    __syncthreads();
    f32x4 acc[2][2];
#pragma unroll
    for (int mf = 0; mf < 2; ++mf)
#pragma unroll
        for (int nf = 0; nf < 2; ++nf) acc[mf][nf] = (f32x4){0.f, 0.f, 0.f, 0.f};
    const short8 zf = {};
    for (int s = 0; s < 36; ++s) {
        int tap = s >> 2, kh = s & 3;
        int dy = tap / 3 - 1, dx = tap % 3 - 1;
        const ushort* bp[2]; bool ok[2]; int lt7[2];
#pragma unroll
        for (int nf = 0; nf < 2; ++nf) {
            int n = tg * 64 + wn * 32 + nf * 16 + l16;
            int ny = (n >> 4) + dy, nx = (n & 15) + dx;
            ok[nf] = ((unsigned)ny < 16u) && ((unsigned)nx < 16u);
            int lrc = min(max(ny - ty0 + 1, 0), 5);
            int nxc = min(max(nx, 0), 15);
            int ltok = lrc * 16 + nxc;
            bp[nf] = &Bs[ltok][0];
            lt7[nf] = ltok & 7;
        }
#pragma unroll
        for (int kc = 0; kc < 2; ++kc) {
            int ua = kc * 4 + kq;
            int ub = kh * 8 + kc * 4 + kq;
            short8 af[2], bfr[2];
#pragma unroll
            for (int mf = 0; mf < 2; ++mf) {
                int o = wm * 32 + mf * 16 + l16;
                af[mf] = *(const short8*)(&As[s & 1][o][(ua ^ (o & 7)) * 8]);
            }
#pragma unroll
            for (int nf = 0; nf < 2; ++nf) {
                short8 v = *(const short8*)(bp[nf] + ((ub ^ lt7[nf]) * 8));
                bfr[nf] = ok[nf] ? v : zf;
            }
#pragma unroll
            for (int mf = 0; mf < 2; ++mf)
#pragma unroll
                for (int nf = 0; nf < 2; ++nf)
                    acc[mf][nf] = __builtin_amdgcn_mfma_f32_16x16x32_bf16(af[mf], bfr[nf], acc[mf][nf], 0, 0, 0);
        }
        __syncthreads();
        if (s + 2 < 36) stageA(s + 2, s & 1);
    }
    float ss[2][4];
#pragma unroll
    for (int mf = 0; mf < 2; ++mf)
#pragma unroll
        for (int r = 0; r < 4; ++r) ss[mf][r] = 0.f;
#pragma unroll
    for (int mf = 0; mf < 2; ++mf)
#pragma unroll
        for (int nf = 0; nf < 2; ++nf)
#pragma unroll
            for (int r = 0; r < 4; ++r) ss[mf][r] += acc[mf][nf][r] * acc[mf][nf][r];
#pragma unroll
    for (int mf = 0; mf < 2; ++mf)
#pragma unroll
        for (int r = 0; r < 4; ++r) {
#pragma unroll
            for (int off = 1; off < 16; off <<= 1) ss[mf][r] += __shfl_xor(ss[mf][r], off, 64);
        }
    if (l16 == 0) {
#pragma unroll
        for (int mf = 0; mf < 2; ++mf)
#pragma unroll
            for (int r = 0; r < 4; ++r)
                atomicAdd(&nrm[b * 256 + og * 64 + wm * 32 + mf * 16 + kq * 4 + r], ss[mf][r]);
    }
    ushort* ob = outp + (size_t)b * 65536;
#pragma unroll
    for (int mf = 0; mf < 2; ++mf)
#pragma unroll
        for (int nf = 0; nf < 2; ++nf) {
            int col = tg * 64 + wn * 32 + nf * 16 + l16;
#pragma unroll
            for (int r = 0; r < 4; ++r) {
                int row = og * 64 + wm * 32 + mf * 16 + kq * 4 + r;
                ob[(size_t)row * 256 + col] = f2bf(acc[mf][nf][r]);
            }
        }
}

// ---- attn v2: 128 blocks (b x 8 c-groups of 32); attnT[d][c] bf16 ------------
__global__ void __launch_bounds__(512) attn_mfma(const ushort* __restrict__ qb,
                                                 const ushort* __restrict__ kTb,
                                                 const float* __restrict__ qnorm,
                                                 const float* __restrict__ knorm,
                                                 ushort* __restrict__ attnT) {
    int blk = blockIdx.x;
    int b = (blk & 7) + 8 * ((blk >> 3) & 1);
    int cg = blk >> 4;                    // 0..7
    int tid = threadIdx.x, wid = tid >> 6, lane = tid & 63;
    int rw = wid & 1, chf = wid >> 1;     // chf 0..3 (64 d each)
    int kq = lane >> 4, l16 = lane & 15;
    int c0w = cg * 32 + rw * 16;
    int lrow = rw * 16 + kq * 4;
    f32x4 acc[4];
#pragma unroll
    for (int nf = 0; nf < 4; ++nf) acc[nf] = (f32x4){0.f, 0.f, 0.f, 0.f};
    const ushort* qp = qb + (size_t)b * 65536;
    const ushort* kp = kTb + (size_t)b * 65536 + (size_t)(chf * 64) * 256;
    for (int kc = 0; kc < 8; ++kc) {
        short8 af = *(const short8*)(qp + (size_t)(c0w + l16) * 256 + kc * 32 + kq * 8);
#pragma unroll
        for (int nf = 0; nf < 4; ++nf) {
            short8 bf = *(const short8*)(kp + (size_t)(nf * 16 + l16) * 256 + kc * 32 + kq * 8);
            acc[nf] = __builtin_amdgcn_mfma_f32_16x16x32_bf16(af, bf, acc[nf], 0, 0, 0);
        }
    }
    float rq[4], rk[4];
#pragma unroll
    for (int r = 0; r < 4; ++r)
        rq[r] = rsqrtf(fmaxf(qnorm[b * 256 + c0w + kq * 4 + r], 1e-24f)) * 0.0625f;
#pragma unroll
    for (int nf = 0; nf < 4; ++nf)
        rk[nf] = rsqrtf(fmaxf(knorm[b * 256 + chf * 64 + nf * 16 + l16], 1e-24f));
#pragma unroll
    for (int nf = 0; nf < 4; ++nf)
#pragma unroll
        for (int r = 0; r < 4; ++r) acc[nf][r] *= rq[r] * rk[nf];
    __shared__ float red[32][4];
    float m4[4], s4[4];
#pragma unroll
    for (int r = 0; r < 4; ++r) {
        float m = -1e30f;
#pragma unroll
        for (int nf = 0; nf < 4; ++nf) m = fmaxf(m, acc[nf][r]);
#pragma unroll
        for (int off = 1; off < 16; off <<= 1) m = fmaxf(m, __shfl_xor(m, off, 64));
        m4[r] = m;
    }
    if (l16 == 0) {
#pragma unroll
        for (int r = 0; r < 4; ++r) red[lrow + r][chf] = m4[r];
    }
    __syncthreads();
#pragma unroll
    for (int r = 0; r < 4; ++r)
        m4[r] = fmaxf(fmaxf(red[lrow + r][0], red[lrow + r][1]),
                      fmaxf(red[lrow + r][2], red[lrow + r][3]));
    __syncthreads();
#pragma unroll
    for (int r = 0; r < 4; ++r) {
        float s = 0.f;
#pragma unroll
        for (int nf = 0; nf < 4; ++nf) {
            float ex = __expf(acc[nf][r] - m4[r]);
            acc[nf][r] = ex;
            s += ex;
        }
#pragma unroll
        for (int off = 1; off < 16; off <<= 1) s += __shfl_xor(s, off, 64);
        s4[r] = s;
    }
    if (l16 == 0) {
#pragma unroll
        for (int r = 0; r < 4; ++r) red[lrow + r][chf] = s4[r];
    }
    __syncthreads();
#pragma unroll
    for (int r = 0; r < 4; ++r) {
        float inv = 1.0f / (red[lrow + r][0] + red[lrow + r][1] +
                            red[lrow + r][2] + red[lrow + r][3]);
#pragma unroll
        for (int nf = 0; nf < 4; ++nf) acc[nf][r] *= inv;
    }
    ushort* ap = attnT + (size_t)b * 65536;
#pragma unroll
    for (int nf = 0; nf < 4; ++nf) {
        int d = chf * 64 + nf * 16 + l16;
        short4v v;
#pragma unroll
        for (int r = 0; r < 4; ++r) v[r] = (short)f2bf(acc[nf][r]);
        *(short4v*)(ap + (size_t)d * 256 + c0w + kq * 4) = v;
    }
}

// ---- mproj v2: 128 blocks (b x 8 o-groups of 32) -----------------------------
__global__ void __launch_bounds__(512) mproj_mfma(const ushort* __restrict__ pbf,
                                                  const ushort* __restrict__ attnT,
                                                  ushort* __restrict__ Mbf) {
    int blk = blockIdx.x;
    int b = (blk & 7) + 8 * ((blk >> 3) & 1);
    int og = blk >> 4;
    int tid = threadIdx.x, wid = tid >> 6, lane = tid & 63;
    int rw = wid & 1, chf = wid >> 1;
    int kq = lane >> 4, l16 = lane & 15;
    int o0w = og * 32 + rw * 16;
    f32x4 acc[4];
#pragma unroll
    for (int nf = 0; nf < 4; ++nf) acc[nf] = (f32x4){0.f, 0.f, 0.f, 0.f};
    const ushort* ap = attnT + (size_t)b * 65536 + (size_t)(chf * 64) * 256;
    for (int kc = 0; kc < 8; ++kc) {
        short8 af = *(const short8*)(pbf + (size_t)(o0w + l16) * 256 + kc * 32 + kq * 8);
#pragma unroll
        for (int nf = 0; nf < 4; ++nf) {
            short8 bf = *(const short8*)(ap + (size_t)(nf * 16 + l16) * 256 + kc * 32 + kq * 8);
            acc[nf] = __builtin_amdgcn_mfma_f32_16x16x32_bf16(af, bf, acc[nf], 0, 0, 0);
        }
    }
    ushort* mb = Mbf + (size_t)b * 65536;
#pragma unroll
    for (int nf = 0; nf < 4; ++nf)
#pragma unroll
        for (int r = 0; r < 4; ++r)
            mb[(size_t)(o0w + kq * 4 + r) * 256 + chf * 64 + nf * 16 + l16] = f2bf(acc[nf][r]);
}

// ---- weff: 144 blocks, bijective XCD map -------------------------------------
__global__ void __launch_bounds__(512) weff_mfma(const ushort* __restrict__ Mbf,
                                                 const ushort* __restrict__ vwT,
                                                 ushort* __restrict__ wbf) {
    int blk = blockIdx.x;
    int wg = (blk % 8) * 18 + blk / 8;   // 144 = 8 x 18, bijective
    int b = wg / 9, j = wg % 9;
    int tid = threadIdx.x;
    int wid = tid >> 6, lane = tid & 63;
    int wm = wid >> 1, wn = wid & 1;
    int kq = lane >> 4, l16 = lane & 15;
    f32x4 acc[4][8];
#pragma unroll
    for (int mf = 0; mf < 4; ++mf)
#pragma unroll
        for (int nf = 0; nf < 8; ++nf) acc[mf][nf] = (f32x4){0.f, 0.f, 0.f, 0.f};
    const ushort* abase = Mbf + (size_t)b * 65536 + (size_t)(wm * 64 + l16) * 256 + kq * 8;
    const ushort* bbase = vwT + (size_t)(j * 256 + wn * 128 + l16) * 256 + kq * 8;
    for (int kc = 0; kc < 8; ++kc) {
        int d0 = kc * 32;
        short8 af[4], bfr[8];
#pragma unroll
        for (int mf = 0; mf < 4; ++mf) af[mf] = *(const short8*)(abase + mf * 16 * 256 + d0);
#pragma unroll
        for (int nf = 0; nf < 8; ++nf) bfr[nf] = *(const short8*)(bbase + nf * 16 * 256 + d0);
#pragma unroll
        for (int mf = 0; mf < 4; ++mf)
#pragma unroll
            for (int nf = 0; nf < 8; ++nf)
                acc[mf][nf] = __builtin_amdgcn_mfma_f32_16x16x32_bf16(af[mf], bfr[nf], acc[mf][nf], 0, 0, 0);
    }
    ushort* wout = wbf + ((size_t)(b * 9 + j)) * 65536;
#pragma unroll
    for (int mf = 0; mf < 4; ++mf) {
        int o = wm * 64 + mf * 16 + kq * 4;
#pragma unroll
        for (int nf = 0; nf < 8; ++nf) {
            int ic = wn * 128 + nf * 16 + l16;
#pragma unroll
            for (int r = 0; r < 4; ++r)
                wout[(size_t)(o + r) * 256 + ic] = f2bf(acc[mf][nf][r]);
        }
    }
}

// ---- big conv v7: et-sourced gload_lds B-stage, R8 geometry, setprio ---------
// grid 512 = b(XCD) x pt(16, 4-row) x oh(2); 8 waves = wr(4 rows) x wo(2 o-halves)
__global__ void __launch_bounds__(512, 4) bigconv_mfma(const ushort* __restrict__ et,
                                                       const ushort* __restrict__ wbf,
                                                       const float* __restrict__ e,
                                                       float* __restrict__ out) {
    int blk = blockIdx.x;
    int ibf = blk >> 3;
    int b = (blk & 7) + 8 * (ibf >> 5);
    int rem = ibf & 31;
    int pt = rem >> 1, oh = rem & 1;
    int y0 = pt * 4;
    int tid = threadIdx.x, wid = tid >> 6, lane = tid & 63;
    int wr = wid >> 1, wo = wid & 1;
    int kq = lane >> 4, l16 = lane & 15;
    __shared__ ushort Bs[6][64][64];   // 48 KB: rows y0-1..y0+4
    __shared__ ushort As[2][128][64];  // 32 KB dbuf
    f32x4 acc[4][4];
#pragma unroll
    for (int mf = 0; mf < 4; ++mf)
#pragma unroll
        for (int nf = 0; nf < 4; ++nf) acc[mf][nf] = (f32x4){0.f, 0.f, 0.f, 0.f};
    const ushort* etb = et + (size_t)b * 1048576;
    const float* eb = e + (size_t)b * NC * NPIX;
    const ushort* wb = wbf + (size_t)b * 589824;
    const short8 zf = {};
    // B-stage invariants: thread -> (px, unit); row = j
    int bpx = (tid >> 3) & 63, bu = tid & 7;
    int bsw = (bu ^ (bpx & 7)) * 8;
    int byc[6];
#pragma unroll
    for (int j = 0; j < 6; ++j) byc[j] = min(max(y0 - 1 + j, 0), 63);
    // A-stage invariants
    int ao[2], asd[2];
#pragma unroll
    for (int j = 0; j < 2; ++j) {
        int du = (j * 8 + wid) * 64 + lane;
        ao[j] = du >> 3;
        asd[j] = (du & 7) ^ (ao[j] & 7);
    }
    auto stageA = [&](int tap, int buf, int ci) {
        const ushort* base = wb + (size_t)tap * 65536 + ci * 64;
#pragma unroll
        for (int j = 0; j < 2; ++j)
            gload_lds16(base + (size_t)(oh * 128 + ao[j]) * 256 + asd[j] * 8,
                        &As[buf][0][0] + (size_t)(j * 8 + wid) * 512);
    };

    for (int ci = 0; ci < 4; ++ci) {
        // ---- stage B from et: 6 rows x 64 px x 64 ch, pure gload_lds ----
        {
#pragma unroll
            for (int j = 0; j < 6; ++j) {
                const ushort* src = etb + (((size_t)(byc[j] * 64 + bpx)) << 8) + ci * 64 + bsw;
                gload_lds16(src, &Bs[0][0][0] + (size_t)(j * 4096 + wid * 512));
            }
        }
        stageA(0, 0, ci);
        __syncthreads();
        for (int tap = 0; tap < 9; ++tap) {
            int cur = tap & 1;
            if (tap < 8) stageA(tap + 1, cur ^ 1, ci);
            {
                int dy = tap / 3 - 1, dx = tap % 3 - 1;
                int rl = wr + dy + 1;
                bool rowok = (unsigned)(y0 + wr + dy) < 64u;
                const ushort* bp[4]; bool ok[4]; int p7[4];
#pragma unroll
                for (int nf = 0; nf < 4; ++nf) {
                    int pxr = nf * 16 + l16 + dx;
                    ok[nf] = rowok && ((unsigned)pxr < 64u);
                    int pxc = min(max(pxr, 0), 63);
                    bp[nf] = &Bs[rl][pxc][0];
                    p7[nf] = pxc & 7;
                }
#pragma unroll
                for (int kc = 0; kc < 2; ++kc) {
                    int sd = kc * 4 + kq;
                    short8 af[4];
#pragma unroll
                    for (int mf = 0; mf < 4; ++mf) {
                        int o = wo * 64 + mf * 16 + l16;
                        af[mf] = *(const short8*)(&As[cur][o][(sd ^ (o & 7)) * 8]);
                    }
                    short8 bfr[4];
#pragma unroll
                    for (int nf = 0; nf < 4; ++nf) {
                        short8 v = *(const short8*)(bp[nf] + (sd ^ p7[nf]) * 8);
                        bfr[nf] = ok[nf] ? v : zf;
                    }
                    __builtin_amdgcn_s_setprio(1);
#pragma unroll
                    for (int mf = 0; mf < 4; ++mf)
#pragma unroll
                        for (int nf = 0; nf < 4; ++nf)
                            acc[mf][nf] = __builtin_amdgcn_mfma_f32_16x16x32_bf16(af[mf], bfr[nf], acc[mf][nf], 0, 0, 0);
                    __builtin_amdgcn_s_setprio(0);
                }
            }
            __syncthreads();
        }
    }
    // ---- epilogue: + residual (f32 from e) ----
    int prow = y0 + wr;
    float* ob = out + (size_t)b * NC * NPIX;
#pragma unroll
    for (int mf = 0; mf < 4; ++mf) {
        int o = oh * 128 + wo * 64 + mf * 16 + kq * 4;
#pragma unroll
        for (int nf = 0; nf < 4; ++nf) {
            int p = prow * 64 + nf * 16 + l16;
#pragma unroll
            for (int r = 0; r < 4; ++r) {
                size_t idx = (size_t)(o + r) * NPIX + p;
                ob[idx] = acc[mf][nf][r] + eb[idx];
            }
        }
    }
}

extern "C" void kernel_launch(void* const* d_in, const int* in_sizes, int n_in,
                              void* d_out, int out_size, void* d_ws, size_t ws_size,
                              hipStream_t stream) {
    const float* e   = (const float*)d_in[0];
    const float* pam = (const float*)d_in[1];
    const float* qw  = (const float*)d_in[2];
    const float* kw  = (const float*)d_in[3];
    const float* vw  = (const float*)d_in[4];
    const float* pw  = (const float*)d_in[5];
    float* out = (float*)d_out;
    float* ws  = (float*)d_ws;

    // layout (f32-slot offsets), total ~60.3 MB:
    ushort* et   = (ushort*)ws;                      // 16,777,216 ushorts (33.5MB)
    ushort* wbf  = (ushort*)(ws + 8388608);          // 9,437,184 ushorts (18.9MB)
    float*  S    = ws + 13107200;
    ushort* maxeT = (ushort*)S;
    ushort* pamT  = (ushort*)(S + 524288);
    ushort* wqT   = (ushort*)(S + 1048576);
    ushort* wkT   = (ushort*)(S + 1343488);
    ushort* pbf   = (ushort*)(S + 1638400);
    ushort* vwT   = (ushort*)(S + 1671168);
    float*  qnorm = S + 1966080;
    float*  knorm = S + 1970176;
    // reuse: qb/kTb inside wbf region (dead before weff writes it)
    ushort* qb    = (ushort*)(ws + 8388608);
    ushort* kTb   = (ushort*)(ws + 8912896);
    ushort* attnT = maxeT;
    ushort* Mbf   = pamT;

    prep_k<<<1105, 256, 0, stream>>>(e, pam, qw, kw, vw, pw,
                                     et, maxeT, pamT, wqT, wkT, pbf, vwT, qnorm, knorm);
    conv16_mfma<<<512, 256, 0, stream>>>(maxeT, pamT, wqT, wkT, qb, kTb, qnorm, knorm);
    attn_mfma<<<128, 512, 0, stream>>>(qb, kTb, qnorm, knorm, attnT);
    mproj_mfma<<<128, 512, 0, stream>>>(pbf, attnT, Mbf);
    weff_mfma<<<144, 512, 0, stream>>>(Mbf, vwT, wbf);
    bigconv_mfma<<<512, 512, 0, stream>>>(et, wbf, e, out);
}

// Round 12
// 171.710 us; speedup vs baseline: 1.2277x; 1.0525x over previous
//
#include <hip/hip_runtime.h>
#include <hip/hip_bf16.h>

#define NB 16
#define NC 256
#define NPIX 4096

typedef __attribute__((ext_vector_type(8))) short short8;
typedef __attribute__((ext_vector_type(4))) short short4v;
typedef __attribute__((ext_vector_type(4))) float f32x4;

static __device__ __forceinline__ ushort f2bf(float f) {
    __hip_bfloat16 h = __float2bfloat16(f);
    return *(ushort*)&h;
}

static __device__ __forceinline__ void gload_lds16(const ushort* g, ushort* l) {
    __builtin_amdgcn_global_load_lds(
        (const __attribute__((address_space(1))) unsigned int*)g,
        (__attribute__((address_space(3))) unsigned int*)l, 16, 0, 0);
}

// ================= prep: fused nhwc+pool (512 blks), transforms ===============
// blocks: [0,512) nhwc+pool (b x py x xhalf) | [512,768) pamtr |
// [768,1280) wtap | [1280,1296) projcast | [1296,1360) vwT | 1360 zero norms
__global__ void __launch_bounds__(256) prep_k(
    const float* __restrict__ e, const float* __restrict__ pam,
    const float* __restrict__ qw, const float* __restrict__ kw,
    const float* __restrict__ vw, const float* __restrict__ pw,
    ushort* __restrict__ et, ushort* __restrict__ maxeT, ushort* __restrict__ pamT,
    ushort* __restrict__ wqT, ushort* __restrict__ wkT,
    ushort* __restrict__ pbf, ushort* __restrict__ vwT,
    float* __restrict__ qnorm, float* __restrict__ knorm) {
    __shared__ float smem[9216];   // 36 KB max across branches
    int blk = blockIdx.x, t = threadIdx.x;
    if (blk < 512) {
        // e NCHW f32 -> et[b][y][x][c] bf16 (XOR transpose) + 4x4 pool
        // block = (b, py 4-row group, xh 32-px half); LDS [256][32] f32 = 32KB
        int b = blk >> 5;
        int py = (blk >> 1) & 15;
        int xh = blk & 1;
        float (*lt)[32] = (float(*)[32])smem;
        float pool[8];
#pragma unroll
        for (int rr = 0; rr < 8; ++rr) pool[rr] = 0.f;
        int px = t & 7;              // pool window x within half
        int x4 = px * 4;
        int cg = t >> 3;             // [0,32)
        for (int r = 0; r < 4; ++r) {
            int y = py * 4 + r;
            if (r) __syncthreads();
            const float* ep = e + (size_t)b * NC * NPIX + y * 64 + xh * 32;
#pragma unroll
            for (int rr = 0; rr < 8; ++rr) {
                int c = rr * 32 + cg;
                float4 v = *(const float4*)(ep + (size_t)c * NPIX + x4);
                pool[rr] += v.x + v.y + v.z + v.w;
                int s = (c >> 3) & 31;
                lt[c][(x4 + 0) ^ s] = v.x;
                lt[c][(x4 + 1) ^ s] = v.y;
                lt[c][(x4 + 2) ^ s] = v.z;
                lt[c][(x4 + 3) ^ s] = v.w;
            }
            __syncthreads();
            int l = t & 31, c0 = l * 8;
            ushort* op = et + ((size_t)((b * 64 + y) * 64) + xh * 32) * 256;
#pragma unroll
            for (int rx = 0; rx < 4; ++rx) {
                int x = rx * 8 + (t >> 5);
                short8 v;
#pragma unroll
                for (int k = 0; k < 8; ++k) v[k] = (short)f2bf(lt[c0 + k][x ^ l]);
                *(short8*)(op + (size_t)x * 256 + c0) = v;
            }
        }
        int tok = py * 16 + xh * 8 + px;
        ushort* md = maxeT + (size_t)b * 65536 + (size_t)tok * 256;
#pragma unroll
        for (int rr = 0; rr < 8; ++rr)
            md[rr * 32 + cg] = f2bf(pool[rr] * 0.0625f);
    } else if (blk < 768) {
        int bb = blk - 512;
        int b = bb >> 4, cg = bb & 15;
        float (*lt)[256] = (float(*)[256])smem;
#pragma unroll
        for (int cc = 0; cc < 16; ++cc)
            lt[cc][t] = pam[(size_t)(b * 256 + cg * 16 + cc) * 256 + t];
        __syncthreads();
        ushort* dstb = pamT + (size_t)b * 65536 + (size_t)t * 256 + cg * 16;
#pragma unroll
        for (int g = 0; g < 2; ++g) {
            short8 v;
#pragma unroll
            for (int k = 0; k < 8; ++k) v[k] = (short)f2bf(lt[g * 8 + k][t]);
            *(short8*)(dstb + g * 8) = v;
        }
    } else if (blk < 1280) {
        int idx = blk - 768;
        const float* src = (idx < 256) ? qw : kw;
        ushort* dst = (idx < 256) ? wqT : wkT;
        int o = idx & 255;
        float wv[9];
#pragma unroll
        for (int j = 0; j < 9; ++j) wv[j] = src[(size_t)o * 2304 + t * 9 + j];
#pragma unroll
        for (int j = 0; j < 9; ++j) dst[(size_t)j * 65536 + (size_t)o * 256 + t] = f2bf(wv[j]);
    } else if (blk < 1296) {
        int base = (blk - 1280) * 4096;
        for (int g = 0; g < 16; ++g) {
            int idx = base + g * 256 + t;
            pbf[idx] = f2bf(pw[idx]);
        }
    } else if (blk < 1360) {
        int d0 = (blk - 1296) * 4;
        float* lt = smem;   // flat [4][2304]
        for (int u = 0; u < 36; ++u) lt[u * 256 + t] = vw[(size_t)d0 * 2304 + u * 256 + t];
        __syncthreads();
#pragma unroll
        for (int r = 0; r < 9; ++r) {
            int idx = r * 256 + t;
            int i = idx / 9, j = idx % 9;
            short4v v;
#pragma unroll
            for (int dd = 0; dd < 4; ++dd) v[dd] = (short)f2bf(lt[dd * 2304 + idx]);
            *(short4v*)(vwT + ((size_t)(j * 256 + i)) * 256 + d0) = v;
        }
    } else {
        for (int g = 0; g < 16; ++g) {
            qnorm[g * 256 + t] = 0.f;
            knorm[g * 256 + t] = 0.f;
        }
    }
}

// ---- conv16 v3: 128-i stages (18, fully unrolled); unnormalized out ----------
__global__ void __launch_bounds__(256, 2) conv16_mfma(const ushort* __restrict__ maxeT,
                                                      const ushort* __restrict__ pamT,
                                                      const ushort* __restrict__ wqT,
                                                      const ushort* __restrict__ wkT,
                                                      ushort* __restrict__ qb,
                                                      ushort* __restrict__ kTb,
                                                      float* __restrict__ qnorm,
                                                      float* __restrict__ knorm) {
    int blk = blockIdx.x;
    int qk = blk >> 8;
    int b  = (blk >> 4) & 15;
    int og = (blk >> 2) & 3;
    int tg = blk & 3;
    const ushort* inT = qk ? pamT : maxeT;
    const ushort* wt  = qk ? wkT : wqT;
    ushort* outp      = qk ? kTb : qb;
    float* nrm        = qk ? knorm : qnorm;
    int tid = threadIdx.x, wid = tid >> 6, lane = tid & 63;
    int wm = wid >> 1, wn = wid & 1;
    int kq = lane >> 4, l16 = lane & 15;
    int ty0 = tg * 4;
    __shared__ ushort Bs[96][256];     // 48 KB
    __shared__ ushort As[2][64][128];  // 32 KB dbuf
    const ushort* itb = inT + (size_t)b * 65536;
    {
#pragma unroll
        for (int j = 0; j < 12; ++j) {
            int d = (j * 4 + wid) * 64 + lane;
            int tok = d >> 5, u = d & 31;
            int lr = tok >> 4, tx = tok & 15;
            int gy = min(max(ty0 - 1 + lr, 0), 15);
            gload_lds16(itb + (gy * 16 + tx) * 256 + ((u ^ (tok & 7)) * 8),
                        &Bs[0][0] + (size_t)(j * 4 + wid) * 512);
        }
    }
    int aoff[4];
#pragma unroll
    for (int j = 0; j < 4; ++j) {
        int d = (j * 4 + wid) * 64 + lane;
        int o = d >> 4, u = d & 15;
        aoff[j] = (og * 64 + o) * 256 + ((u ^ (o & 7)) * 8);
    }
    auto stageA = [&](int s, int buf) {
        const ushort* base = wt + (size_t)(s >> 1) * 65536 + (s & 1) * 128;
#pragma unroll
        for (int j = 0; j < 4; ++j)
            gload_lds16(base + aoff[j], &As[buf][0][0] + (size_t)(j * 4 + wid) * 512);
    };
    stageA(0, 0);
    stageA(1, 1);
    __syncthreads();
    f32x4 acc[2][2];
#pragma unroll
    for (int mf = 0; mf < 2; ++mf)
#pragma unroll
        for (int nf = 0; nf < 2; ++nf) acc[mf][nf] = (f32x4){0.f, 0.f, 0.f, 0.f};
    const short8 zf = {};
#pragma unroll
    for (int s = 0; s < 18; ++s) {
        int tap = s >> 1, half = s & 1;
        int dy = tap / 3 - 1, dx = tap % 3 - 1;
        const ushort* bp[2]; bool ok[2]; int lt7[2];
#pragma unroll
        for (int nf = 0; nf < 2; ++nf) {
            int n = tg * 64 + wn * 32 + nf * 16 + l16;
            int ny = (n >> 4) + dy, nx = (n & 15) + dx;
            ok[nf] = ((unsigned)ny < 16u) && ((unsigned)nx < 16u);
            int lrc = min(max(ny - ty0 + 1, 0), 5);
            int nxc = min(max(nx, 0), 15);
            int ltok = lrc * 16 + nxc;
            bp[nf] = &Bs[ltok][0];
            lt7[nf] = ltok & 7;
        }
#pragma unroll
        for (int kc = 0; kc < 4; ++kc) {
            int ua = kc * 4 + kq;
            int ub = half * 16 + kc * 4 + kq;
            short8 af[2], bfr[2];
#pragma unroll
            for (int mf = 0; mf < 2; ++mf) {
                int o = wm * 32 + mf * 16 + l16;
                af[mf] = *(const short8*)(&As[s & 1][o][(ua ^ (o & 7)) * 8]);
            }
#pragma unroll
            for (int nf = 0; nf < 2; ++nf) {
                short8 v = *(const short8*)(bp[nf] + ((ub ^ lt7[nf]) * 8));
                bfr[nf] = ok[nf] ? v : zf;
            }
#pragma unroll
            for (int mf = 0; mf < 2; ++mf)
#pragma unroll
                for (int nf = 0; nf < 2; ++nf)
                    acc[mf][nf] = __builtin_amdgcn_mfma_f32_16x16x32_bf16(af[mf], bfr[nf], acc[mf][nf], 0, 0, 0);
        }
        __syncthreads();
        if (s + 2 < 18) stageA(s + 2, s & 1);
    }
    float ss[2][4];
#pragma unroll
    for (int mf = 0; mf < 2; ++mf)
#pragma unroll
        for (int r = 0; r < 4; ++r) ss[mf][r] = 0.f;
#pragma unroll
    for (int mf = 0; mf < 2; ++mf)
#pragma unroll
        for (int nf = 0; nf < 2; ++nf)
#pragma unroll
            for (int r = 0; r < 4; ++r) ss[mf][r] += acc[mf][nf][r] * acc[mf][nf][r];
#pragma unroll
    for (int mf = 0; mf < 2; ++mf)
#pragma unroll
        for (int r = 0; r < 4; ++r) {
#pragma unroll
            for (int off = 1; off < 16; off <<= 1) ss[mf][r] += __shfl_xor(ss[mf][r], off, 64);
        }
    if (l16 == 0) {
#pragma unroll
        for (int mf = 0; mf < 2; ++mf)
#pragma unroll
            for (int r = 0; r < 4; ++r)
                atomicAdd(&nrm[b * 256 + og * 64 + wm * 32 + mf * 16 + kq * 4 + r], ss[mf][r]);
    }
    ushort* ob = outp + (size_t)b * 65536;
#pragma unroll
    for (int mf = 0; mf < 2; ++mf)
#pragma unroll
        for (int nf = 0; nf < 2; ++nf) {
            int col = tg * 64 + wn * 32 + nf * 16 + l16;
#pragma unroll
            for (int r = 0; r < 4; ++r) {
                int row = og * 64 + wm * 32 + mf * 16 + kq * 4 + r;
                ob[(size_t)row * 256 + col] = f2bf(acc[mf][nf][r]);
            }
        }
}

// ---- attn: 128 blocks (b x 8 c-groups of 32); attnT[d][c] bf16 ---------------
__global__ void __launch_bounds__(512) attn_mfma(const ushort* __restrict__ qb,
                                                 const ushort* __restrict__ kTb,
                                                 const float* __restrict__ qnorm,
                                                 const float* __restrict__ knorm,
                                                 ushort* __restrict__ attnT) {
    int blk = blockIdx.x;
    int b = (blk & 7) + 8 * ((blk >> 3) & 1);
    int cg = blk >> 4;
    int tid = threadIdx.x, wid = tid >> 6, lane = tid & 63;
    int rw = wid & 1, chf = wid >> 1;
    int kq = lane >> 4, l16 = lane & 15;
    int c0w = cg * 32 + rw * 16;
    int lrow = rw * 16 + kq * 4;
    f32x4 acc[4];
#pragma unroll
    for (int nf = 0; nf < 4; ++nf) acc[nf] = (f32x4){0.f, 0.f, 0.f, 0.f};
    const ushort* qp = qb + (size_t)b * 65536;
    const ushort* kp = kTb + (size_t)b * 65536 + (size_t)(chf * 64) * 256;
    for (int kc = 0; kc < 8; ++kc) {
        short8 af = *(const short8*)(qp + (size_t)(c0w + l16) * 256 + kc * 32 + kq * 8);
#pragma unroll
        for (int nf = 0; nf < 4; ++nf) {
            short8 bf = *(const short8*)(kp + (size_t)(nf * 16 + l16) * 256 + kc * 32 + kq * 8);
            acc[nf] = __builtin_amdgcn_mfma_f32_16x16x32_bf16(af, bf, acc[nf], 0, 0, 0);
        }
    }
    float rq[4], rk[4];
#pragma unroll
    for (int r = 0; r < 4; ++r)
        rq[r] = rsqrtf(fmaxf(qnorm[b * 256 + c0w + kq * 4 + r], 1e-24f)) * 0.0625f;
#pragma unroll
    for (int nf = 0; nf < 4; ++nf)
        rk[nf] = rsqrtf(fmaxf(knorm[b * 256 + chf * 64 + nf * 16 + l16], 1e-24f));
#pragma unroll
    for (int nf = 0; nf < 4; ++nf)
#pragma unroll
        for (int r = 0; r < 4; ++r) acc[nf][r] *= rq[r] * rk[nf];
    __shared__ float red[32][4];
    float m4[4], s4[4];
#pragma unroll
    for (int r = 0; r < 4; ++r) {
        float m = -1e30f;
#pragma unroll
        for (int nf = 0; nf < 4; ++nf) m = fmaxf(m, acc[nf][r]);
#pragma unroll
        for (int off = 1; off < 16; off <<= 1) m = fmaxf(m, __shfl_xor(m, off, 64));
        m4[r] = m;
    }
    if (l16 == 0) {
#pragma unroll
        for (int r = 0; r < 4; ++r) red[lrow + r][chf] = m4[r];
    }
    __syncthreads();
#pragma unroll
    for (int r = 0; r < 4; ++r)
        m4[r] = fmaxf(fmaxf(red[lrow + r][0], red[lrow + r][1]),
                      fmaxf(red[lrow + r][2], red[lrow + r][3]));
    __syncthreads();
#pragma unroll
    for (int r = 0; r < 4; ++r) {
        float s = 0.f;
#pragma unroll
        for (int nf = 0; nf < 4; ++nf) {
            float ex = __expf(acc[nf][r] - m4[r]);
            acc[nf][r] = ex;
            s += ex;
        }
#pragma unroll
        for (int off = 1; off < 16; off <<= 1) s += __shfl_xor(s, off, 64);
        s4[r] = s;
    }
    if (l16 == 0) {
#pragma unroll
        for (int r = 0; r < 4; ++r) red[lrow + r][chf] = s4[r];
    }
    __syncthreads();
#pragma unroll
    for (int r = 0; r < 4; ++r) {
        float inv = 1.0f / (red[lrow + r][0] + red[lrow + r][1] +
                            red[lrow + r][2] + red[lrow + r][3]);
#pragma unroll
        for (int nf = 0; nf < 4; ++nf) acc[nf][r] *= inv;
    }
    ushort* ap = attnT + (size_t)b * 65536;
#pragma unroll
    for (int nf = 0; nf < 4; ++nf) {
        int d = chf * 64 + nf * 16 + l16;
        short4v v;
#pragma unroll
        for (int r = 0; r < 4; ++r) v[r] = (short)f2bf(acc[nf][r]);
        *(short4v*)(ap + (size_t)d * 256 + c0w + kq * 4) = v;
    }
}

// ---- mproj: 128 blocks (b x 8 o-groups of 32) --------------------------------
__global__ void __launch_bounds__(512) mproj_mfma(const ushort* __restrict__ pbf,
                                                  const ushort* __restrict__ attnT,
                                                  ushort* __restrict__ Mbf) {
    int blk = blockIdx.x;
    int b = (blk & 7) + 8 * ((blk >> 3) & 1);
    int og = blk >> 4;
    int tid = threadIdx.x, wid = tid >> 6, lane = tid & 63;
    int rw = wid & 1, chf = wid >> 1;
    int kq = lane >> 4, l16 = lane & 15;
    int o0w = og * 32 + rw * 16;
    f32x4 acc[4];
#pragma unroll
    for (int nf = 0; nf < 4; ++nf) acc[nf] = (f32x4){0.f, 0.f, 0.f, 0.f};
    const ushort* ap = attnT + (size_t)b * 65536 + (size_t)(chf * 64) * 256;
    for (int kc = 0; kc < 8; ++kc) {
        short8 af = *(const short8*)(pbf + (size_t)(o0w + l16) * 256 + kc * 32 + kq * 8);
#pragma unroll
        for (int nf = 0; nf < 4; ++nf) {
            short8 bf = *(const short8*)(ap + (size_t)(nf * 16 + l16) * 256 + kc * 32 + kq * 8);
            acc[nf] = __builtin_amdgcn_mfma_f32_16x16x32_bf16(af, bf, acc[nf], 0, 0, 0);
        }
    }
    ushort* mb = Mbf + (size_t)b * 65536;
#pragma unroll
    for (int nf = 0; nf < 4; ++nf)
#pragma unroll
        for (int r = 0; r < 4; ++r)
            mb[(size_t)(o0w + kq * 4 + r) * 256 + chf * 64 + nf * 16 + l16] = f2bf(acc[nf][r]);
}

// ---- weff: 144 blocks, bijective XCD map -------------------------------------
__global__ void __launch_bounds__(512) weff_mfma(const ushort* __restrict__ Mbf,
                                                 const ushort* __restrict__ vwT,
                                                 ushort* __restrict__ wbf) {
    int blk = blockIdx.x;
    int wg = (blk % 8) * 18 + blk / 8;
    int b = wg / 9, j = wg % 9;
    int tid = threadIdx.x;
    int wid = tid >> 6, lane = tid & 63;
    int wm = wid >> 1, wn = wid & 1;
    int kq = lane >> 4, l16 = lane & 15;
    f32x4 acc[4][8];
#pragma unroll
    for (int mf = 0; mf < 4; ++mf)
#pragma unroll
        for (int nf = 0; nf < 8; ++nf) acc[mf][nf] = (f32x4){0.f, 0.f, 0.f, 0.f};
    const ushort* abase = Mbf + (size_t)b * 65536 + (size_t)(wm * 64 + l16) * 256 + kq * 8;
    const ushort* bbase = vwT + (size_t)(j * 256 + wn * 128 + l16) * 256 + kq * 8;
    for (int kc = 0; kc < 8; ++kc) {
        int d0 = kc * 32;
        short8 af[4], bfr[8];
#pragma unroll
        for (int mf = 0; mf < 4; ++mf) af[mf] = *(const short8*)(abase + mf * 16 * 256 + d0);
#pragma unroll
        for (int nf = 0; nf < 8; ++nf) bfr[nf] = *(const short8*)(bbase + nf * 16 * 256 + d0);
#pragma unroll
        for (int mf = 0; mf < 4; ++mf)
#pragma unroll
            for (int nf = 0; nf < 8; ++nf)
                acc[mf][nf] = __builtin_amdgcn_mfma_f32_16x16x32_bf16(af[mf], bfr[nf], acc[mf][nf], 0, 0, 0);
    }
    ushort* wout = wbf + ((size_t)(b * 9 + j)) * 65536;
#pragma unroll
    for (int mf = 0; mf < 4; ++mf) {
        int o = wm * 64 + mf * 16 + kq * 4;
#pragma unroll
        for (int nf = 0; nf < 8; ++nf) {
            int ic = wn * 128 + nf * 16 + l16;
#pragma unroll
            for (int r = 0; r < 4; ++r)
                wout[(size_t)(o + r) * 256 + ic] = f2bf(acc[mf][nf][r]);
        }
    }
}

// ---- big conv v8: et-sourced B, unrolled taps, setprio -----------------------
__global__ void __launch_bounds__(512, 4) bigconv_mfma(const ushort* __restrict__ et,
                                                       const ushort* __restrict__ wbf,
                                                       const float* __restrict__ e,
                                                       float* __restrict__ out) {
    int blk = blockIdx.x;
    int ibf = blk >> 3;
    int b = (blk & 7) + 8 * (ibf >> 5);
    int rem = ibf & 31;
    int pt = rem >> 1, oh = rem & 1;
    int y0 = pt * 4;
    int tid = threadIdx.x, wid = tid >> 6, lane = tid & 63;
    int wr = wid >> 1, wo = wid & 1;
    int kq = lane >> 4, l16 = lane & 15;
    __shared__ ushort Bs[6][64][64];
    __shared__ ushort As[2][128][64];
    f32x4 acc[4][4];
#pragma unroll
    for (int mf = 0; mf < 4; ++mf)
#pragma unroll
        for (int nf = 0; nf < 4; ++nf) acc[mf][nf] = (f32x4){0.f, 0.f, 0.f, 0.f};
    const ushort* etb = et + (size_t)b * 1048576;
    const float* eb = e + (size_t)b * NC * NPIX;
    const ushort* wb = wbf + (size_t)b * 589824;
    const short8 zf = {};
    int bpx = (tid >> 3) & 63, bu = tid & 7;
    int bsw = (bu ^ (bpx & 7)) * 8;
    int byc[6];
#pragma unroll
    for (int j = 0; j < 6; ++j) byc[j] = min(max(y0 - 1 + j, 0), 63);
    int ao[2], asd[2];
#pragma unroll
    for (int j = 0; j < 2; ++j) {
        int du = (j * 8 + wid) * 64 + lane;
        ao[j] = du >> 3;
        asd[j] = (du & 7) ^ (ao[j] & 7);
    }
    auto stageA = [&](int tap, int buf, int ci) {
        const ushort* base = wb + (size_t)tap * 65536 + ci * 64;
#pragma unroll
        for (int j = 0; j < 2; ++j)
            gload_lds16(base + (size_t)(oh * 128 + ao[j]) * 256 + asd[j] * 8,
                        &As[buf][0][0] + (size_t)(j * 8 + wid) * 512);
    };

    for (int ci = 0; ci < 4; ++ci) {
        {
#pragma unroll
            for (int j = 0; j < 6; ++j) {
                const ushort* src = etb + (((size_t)(byc[j] * 64 + bpx)) << 8) + ci * 64 + bsw;
                gload_lds16(src, &Bs[0][0][0] + (size_t)(j * 4096 + wid * 512));
            }
        }
        stageA(0, 0, ci);
        __syncthreads();
#pragma unroll
        for (int tap = 0; tap < 9; ++tap) {
            int cur = tap & 1;
            if (tap < 8) stageA(tap + 1, cur ^ 1, ci);
            {
                const int dy = tap / 3 - 1, dx = tap % 3 - 1;
                const int rl = wr + dy + 1;
                const bool rowok = (unsigned)(y0 + wr + dy) < 64u;
                const ushort* bp[4]; bool ok[4]; int p7[4];
#pragma unroll
                for (int nf = 0; nf < 4; ++nf) {
                    int pxr = nf * 16 + l16 + dx;
                    ok[nf] = rowok && ((unsigned)pxr < 64u);
                    int pxc = min(max(pxr, 0), 63);
                    bp[nf] = &Bs[rl][pxc][0];
                    p7[nf] = pxc & 7;
                }
#pragma unroll
                for (int kc = 0; kc < 2; ++kc) {
                    int sd = kc * 4 + kq;
                    short8 af[4];
#pragma unroll
                    for (int mf = 0; mf < 4; ++mf) {
                        int o = wo * 64 + mf * 16 + l16;
                        af[mf] = *(const short8*)(&As[cur][o][(sd ^ (o & 7)) * 8]);
                    }
                    short8 bfr[4];
#pragma unroll
                    for (int nf = 0; nf < 4; ++nf) {
                        short8 v = *(const short8*)(bp[nf] + (sd ^ p7[nf]) * 8);
                        bfr[nf] = ok[nf] ? v : zf;
                    }
                    __builtin_amdgcn_s_setprio(1);
#pragma unroll
                    for (int mf = 0; mf < 4; ++mf)
#pragma unroll
                        for (int nf = 0; nf < 4; ++nf)
                            acc[mf][nf] = __builtin_amdgcn_mfma_f32_16x16x32_bf16(af[mf], bfr[nf], acc[mf][nf], 0, 0, 0);
                    __builtin_amdgcn_s_setprio(0);
                }
            }
            __syncthreads();
        }
    }
    int prow = y0 + wr;
    float* ob = out + (size_t)b * NC * NPIX;
#pragma unroll
    for (int mf = 0; mf < 4; ++mf) {
        int o = oh * 128 + wo * 64 + mf * 16 + kq * 4;
#pragma unroll
        for (int nf = 0; nf < 4; ++nf) {
            int p = prow * 64 + nf * 16 + l16;
#pragma unroll
            for (int r = 0; r < 4; ++r) {
                size_t idx = (size_t)(o + r) * NPIX + p;
                ob[idx] = acc[mf][nf][r] + eb[idx];
            }
        }
    }
}

extern "C" void kernel_launch(void* const* d_in, const int* in_sizes, int n_in,
                              void* d_out, int out_size, void* d_ws, size_t ws_size,
                              hipStream_t stream) {
    const float* e   = (const float*)d_in[0];
    const float* pam = (const float*)d_in[1];
    const float* qw  = (const float*)d_in[2];
    const float* kw  = (const float*)d_in[3];
    const float* vw  = (const float*)d_in[4];
    const float* pw  = (const float*)d_in[5];
    float* out = (float*)d_out;
    float* ws  = (float*)d_ws;

    ushort* et   = (ushort*)ws;                      // 16,777,216 ushorts (33.5MB)
    ushort* wbf  = (ushort*)(ws + 8388608);          // 9,437,184 ushorts (18.9MB)
    float*  S    = ws + 13107200;
    ushort* maxeT = (ushort*)S;
    ushort* pamT  = (ushort*)(S + 524288);
    ushort* wqT   = (ushort*)(S + 1048576);
    ushort* wkT   = (ushort*)(S + 1343488);
    ushort* pbf   = (ushort*)(S + 1638400);
    ushort* vwT   = (ushort*)(S + 1671168);
    float*  qnorm = S + 1966080;
    float*  knorm = S + 1970176;
    ushort* qb    = (ushort*)(ws + 8388608);
    ushort* kTb   = (ushort*)(ws + 8912896);
    ushort* attnT = maxeT;
    ushort* Mbf   = pamT;

    prep_k<<<1361, 256, 0, stream>>>(e, pam, qw, kw, vw, pw,
                                     et, maxeT, pamT, wqT, wkT, pbf, vwT, qnorm, knorm);
    conv16_mfma<<<512, 256, 0, stream>>>(maxeT, pamT, wqT, wkT, qb, kTb, qnorm, knorm);
    attn_mfma<<<128, 512, 0, stream>>>(qb, kTb, qnorm, knorm, attnT);
    mproj_mfma<<<128, 512, 0, stream>>>(pbf, attnT, Mbf);
    weff_mfma<<<144, 512, 0, stream>>>(Mbf, vwT, wbf);
    bigconv_mfma<<<512, 512, 0, stream>>>(et, wbf, e, out);
}